// Round 1
// baseline (217.882 us; speedup 1.0000x reference)
//
#include <hip/hip_runtime.h>
#include <math.h>

#define WIDTH 512
#define HALF  256
#define DEPTH 32
#define BATCH 65536
#define RPW   8   // rows per wave

// Precomputed per-(depth, physical position) parameters, stored in the
// physical order the main kernel reads them (coalesced):
//   entry index = d*512 + slot*64 + lane   for physical p = lane*8 + slot
// T1 = {A = a*cos(th), S = +-a*sin(th), B = sinh(bias), cc}
// T2 = invk = exp(-curv)
__device__ float4 g_T1[DEPTH * WIDTH];
__device__ float  g_T2[DEPTH * WIDTH];

__global__ __launch_bounds__(256) void precompute_kernel(
    const float* __restrict__ thetas, const float* __restrict__ biases,
    const float* __restrict__ slopes1, const float* __restrict__ slopes2,
    const float* __restrict__ curvatures) {
  int tid = blockIdx.x * 256 + threadIdx.x;
  if (tid >= DEPTH * WIDTH) return;
  int d = tid >> 9;
  int p = tid & 511;
  // logical column of physical p AFTER layer d = rotl9(p, d+1)
  int rot = (d + 1) % 9;
  int j = ((p << rot) | (p >> (9 - rot))) & 511;  // rot==0 -> j=p (p>>9==0)
  int i = j >> 1;          // theta index
  int role = j & 1;        // 0 = n0 (x0*c + x1*s), 1 = n1 (-x0*s + x1*c)
  float th = thetas[d * HALF + i];
  float c = cosf(th), s = sinf(th);
  float m1 = expf(slopes1[d * WIDTH + j]);
  float m2 = expf(slopes2[d * WIDTH + j]);
  float a  = 0.5f * (m1 + m2);
  float cc = (m2 - m1) / (m1 + m2);   // (m2-m1)/(2a)
  float b  = sinhf(biases[d * WIDTH + j]);
  float invk = expf(-curvatures[d * WIDTH + j]);
  float A = a * c;
  float S = role ? (-a * s) : (a * s);
  int q = d * WIDTH + ((p & 7) * 64 + (p >> 3));  // physical storage order
  g_T1[q] = make_float4(A, S, b, cc);
  g_T2[q] = invk;
}

#if __has_builtin(__builtin_amdgcn_sqrtf)
#define FAST_SQRT(x) __builtin_amdgcn_sqrtf(x)
#else
#define FAST_SQRT(x) sqrtf(x)
#endif

__device__ __forceinline__ float stepf(float xs, float v, float4 P, float ik) {
  float u = fmaf(xs, P.x, fmaf(v, P.y, -P.z));
  float t = fmaf(u, u, ik);
  return fmaf(P.w, FAST_SQRT(t), u);
}

__device__ __forceinline__ void loadp(int d, int lane, float4 (&P)[8], float (&IK)[8]) {
  const float4* __restrict__ t1p = &g_T1[d * WIDTH + lane];
  const float*  __restrict__ t2p = &g_T2[d * WIDTH + lane];
#pragma unroll
  for (int s = 0; s < 8; ++s) { P[s] = t1p[s * 64]; IK[s] = t2p[s * 64]; }
}

// K = physical bit index on which this layer pairs.
// K >= 3: cross-lane (shfl mask 1<<(K-3)); K < 3: intra-thread slot pair.
template <int K>
__device__ __forceinline__ void do_layer(float (&x)[8][RPW], const float4 (&P)[8],
                                         const float (&IK)[8]) {
  if constexpr (K >= 3) {
    constexpr int m = 1 << (K - 3);
#pragma unroll
    for (int s = 0; s < 8; ++s) {
#pragma unroll
      for (int r = 0; r < RPW; ++r) {
        float xs = x[s][r];
        float v = __shfl_xor(xs, m, 64);
        x[s][r] = stepf(xs, v, P[s], IK[s]);
      }
    }
  } else {
    constexpr int SX = 1 << K;
#pragma unroll
    for (int s0 = 0; s0 < 8; ++s0) {
      if (s0 & SX) continue;
      constexpr int dummy = 0; (void)dummy;
      const int s1 = s0 | SX;
#pragma unroll
      for (int r = 0; r < RPW; ++r) {
        float v0 = x[s0][r], v1 = x[s1][r];
        float n0 = stepf(v0, v1, P[s0], IK[s0]);
        float n1 = stepf(v1, v0, P[s1], IK[s1]);
        x[s0][r] = n0;
        x[s1][r] = n1;
      }
    }
  }
}

__global__ __launch_bounds__(256) void net_kernel(const float* __restrict__ X,
                                                  float* __restrict__ out) {
  const int lane = threadIdx.x & 63;
  const int wv = blockIdx.x * 4 + (threadIdx.x >> 6);
  const size_t row0 = (size_t)wv * RPW;

  // physical position of x[s][r] within the row: p = lane*8 + s
  float x[8][RPW];
  const float4* __restrict__ Xv =
      reinterpret_cast<const float4*>(X + row0 * WIDTH);
#pragma unroll
  for (int r = 0; r < RPW; ++r) {
    float4 a = Xv[r * (WIDTH / 4) + lane * 2];
    float4 b = Xv[r * (WIDTH / 4) + lane * 2 + 1];
    x[0][r] = a.x; x[1][r] = a.y; x[2][r] = a.z; x[3][r] = a.w;
    x[4][r] = b.x; x[5][r] = b.y; x[6][r] = b.z; x[7][r] = b.w;
  }

  float4 P[8];
  float IK[8];
  // layer d pairs on physical bit k = 8 - (d % 9); pattern period 9
#define RUN_LAYER(DD)                                \
  do {                                               \
    if (d0 + DD < DEPTH) {                           \
      loadp(d0 + DD, lane, P, IK);                   \
      do_layer<8 - DD>(x, P, IK);                    \
    }                                                \
  } while (0)

  for (int d0 = 0; d0 < DEPTH; d0 += 9) {
    RUN_LAYER(0); RUN_LAYER(1); RUN_LAYER(2);
    RUN_LAYER(3); RUN_LAYER(4); RUN_LAYER(5);
    RUN_LAYER(6); RUN_LAYER(7); RUN_LAYER(8);
  }
#undef RUN_LAYER

  // final logical column of physical p is rotl9(p, 32 mod 9 = 5)
  float* __restrict__ O = out + row0 * WIDTH;
#pragma unroll
  for (int s = 0; s < 8; ++s) {
    const int p = lane * 8 + s;
    const int cfin = ((p << 5) | (p >> 4)) & 511;
#pragma unroll
    for (int r = 0; r < RPW; ++r) O[r * WIDTH + cfin] = x[s][r];
  }
}

extern "C" void kernel_launch(void* const* d_in, const int* in_sizes, int n_in,
                              void* d_out, int out_size, void* d_ws, size_t ws_size,
                              hipStream_t stream) {
  const float* X          = (const float*)d_in[0];
  const float* thetas     = (const float*)d_in[1];
  const float* biases     = (const float*)d_in[2];
  const float* slopes1    = (const float*)d_in[3];
  const float* slopes2    = (const float*)d_in[4];
  const float* curvatures = (const float*)d_in[5];
  float* out = (float*)d_out;

  hipLaunchKernelGGL(precompute_kernel, dim3((DEPTH * WIDTH + 255) / 256),
                     dim3(256), 0, stream, thetas, biases, slopes1, slopes2,
                     curvatures);
  hipLaunchKernelGGL(net_kernel, dim3(BATCH / (RPW * 4)), dim3(256), 0, stream,
                     X, out);
}